// Round 5
// baseline (290.081 us; speedup 1.0000x reference)
//
#include <hip/hip_runtime.h>
#include <math.h>

#define BB      2
#define C_CT    128
#define CB      32
#define NN      180
#define VV      13824      // 24*24*24
#define TILE    16         // voxels per block
#define NTILES  (VV / TILE)   // 864 per batch -> 1728 blocks total
#define GR      4          // n-groups (one per wave)
#define NPG     45         // NN / GR
#define THREADS 256

typedef float vfloat4 __attribute__((ext_vector_type(4)));

__global__ __launch_bounds__(THREADS, 4)
void vmat_attn_kernel(const float* __restrict__ ct, const float* __restrict__ beam,
                      const float* __restrict__ qw, const float* __restrict__ qb,
                      const float* __restrict__ gam, const float* __restrict__ bet,
                      float* __restrict__ out)
{
    // Union region (25088 B):
    //  phase 1-2: qw_t[128][33] (16896 B) + ct_s[128][16] (8192 B)
    //  phase 3+ : W_t[16][180] (11520 B) + Pacc[4][32][16] (8192 B) + l_prt[4][16] (256 B)
    __shared__ __align__(16) float uni[6272];
    __shared__ __align__(16) float q_s[TILE * CB];   // q_s[v][o]
    __shared__ float inv_l_s[TILE];
    __shared__ float qb_s[CB], gam_s[CB], bet_s[CB];

    float* qw_t  = uni;                   // [128][33] (+1 pad kills store conflicts)
    float* ct_s  = uni + 128 * 33;        // [128][16]
    float* W_t   = uni;                   // [16][180] unnormalized weights
    float* Pacc  = uni + 2880;            // [4][32][16]
    float* l_prt = uni + 2880 + 2048;     // [4][16]

    const int t   = threadIdx.x;
    const int bid = blockIdx.x;
    const int b   = bid / NTILES;
    const int v0  = (bid % NTILES) * TILE;

    // ---- phase 1: stage qw (transposed, padded) + ct tile + params ----
    for (int i = t; i < CB * C_CT; i += THREADS) {
        const int o = i >> 7, c = i & 127;
        qw_t[c * 33 + o] = qw[i];
    }
    {
        const float* ctbase = ct + (size_t)b * C_CT * VV + v0;
        for (int i = t; i < C_CT * 4; i += THREADS) {   // 512 float4
            const int c = i >> 2, qd = i & 3;
            *reinterpret_cast<vfloat4*>(&ct_s[c * TILE + qd * 4]) =
                *reinterpret_cast<const vfloat4*>(ctbase + (size_t)c * VV + qd * 4);
        }
    }
    if (t < CB) { qb_s[t] = qb[t]; gam_s[t] = gam[t]; bet_s[t] = bet[t]; }
    __syncthreads();

    // ---- phase 2: q = qw @ ct tile (32x16x128 LDS GEMM; 2 outputs/thread) ----
    {
        const int o  = t & 31;
        const int va = t >> 5;               // 0..7 ; second voxel = va+8
        float a0 = qb_s[o], a1 = qb_s[o];
        for (int k = 0; k < C_CT; ++k) {
            const float wk = qw_t[k * 33 + o];            // conflict-free (bank o+k)
            a0 = fmaf(wk, ct_s[k * TILE + va], a0);       // broadcast
            a1 = fmaf(wk, ct_s[k * TILE + va + 8], a1);
        }
        q_s[va * CB + o]       = a0;
        q_s[(va + 8) * CB + o] = a1;
    }
    __syncthreads();   // uni reused as W_t/Pacc below

    // ---- phase 3: fused logits + exp + weighted accum (waves split N) ----
    const int lane = t & 63;
    const int g    = t >> 6;        // wave = n-group
    const int vq   = lane & 3;      // voxel quad (voxels vq*4..vq*4+3)
    const int cg   = lane >> 2;     // 0..15 ; channels cg and cg+16

    float q0[4], q1[4];
    #pragma unroll
    for (int j = 0; j < 4; ++j) {
        q0[j] = q_s[(vq * 4 + j) * CB + cg];
        q1[j] = q_s[(vq * 4 + j) * CB + cg + 16];
    }

    const float scale = 0.17677669529663687f;  // 32^-0.5
    float acc0[4] = {0.f, 0.f, 0.f, 0.f};
    float acc1[4] = {0.f, 0.f, 0.f, 0.f};
    float l0 = 0.f, l1 = 0.f, l2 = 0.f, l3 = 0.f;
    const float* bpc = beam + ((size_t)(b * NN + g * NPG) * CB + cg) * VV + v0 + vq * 4;

    vfloat4 kA0, kA1, kB0, kB1;
    auto loadK = [&](vfloat4& x0, vfloat4& x1, int i) {
        const float* p = bpc + (size_t)i * (CB * VV);
        x0 = __builtin_nontemporal_load(reinterpret_cast<const vfloat4*>(p));
        x1 = __builtin_nontemporal_load(reinterpret_cast<const vfloat4*>(p + 16 * VV));
    };
    auto computeK = [&](const vfloat4& k0, const vfloat4& k1, int i) {
        float p0 = q0[0] * k0.x + q1[0] * k1.x;
        float p1 = q0[1] * k0.y + q1[1] * k1.y;
        float p2 = q0[2] * k0.z + q1[2] * k1.z;
        float p3 = q0[3] * k0.w + q1[3] * k1.w;
        p0 += __shfl_xor(p0, 4);  p1 += __shfl_xor(p1, 4);
        p2 += __shfl_xor(p2, 4);  p3 += __shfl_xor(p3, 4);
        p0 += __shfl_xor(p0, 8);  p1 += __shfl_xor(p1, 8);
        p2 += __shfl_xor(p2, 8);  p3 += __shfl_xor(p3, 8);
        p0 += __shfl_xor(p0, 16); p1 += __shfl_xor(p1, 16);
        p2 += __shfl_xor(p2, 16); p3 += __shfl_xor(p3, 16);
        p0 += __shfl_xor(p0, 32); p1 += __shfl_xor(p1, 32);
        p2 += __shfl_xor(p2, 32); p3 += __shfl_xor(p3, 32);
        const float w0 = __expf(fminf(p0 * scale, 60.f));
        const float w1 = __expf(fminf(p1 * scale, 60.f));
        const float w2 = __expf(fminf(p2 * scale, 60.f));
        const float w3 = __expf(fminf(p3 * scale, 60.f));
        if (cg < 4) {   // lane (vq, cg<4) stores voxel vq*4+cg's weight (~2-way banks)
            const float wsel = cg == 0 ? w0 : cg == 1 ? w1 : cg == 2 ? w2 : w3;
            W_t[(vq * 4 + cg) * NN + (g * NPG + i)] = wsel;
        }
        l0 += w0; l1 += w1; l2 += w2; l3 += w3;
        acc0[0] = fmaf(w0, k0.x, acc0[0]); acc1[0] = fmaf(w0, k1.x, acc1[0]);
        acc0[1] = fmaf(w1, k0.y, acc0[1]); acc1[1] = fmaf(w1, k1.y, acc1[1]);
        acc0[2] = fmaf(w2, k0.z, acc0[2]); acc1[2] = fmaf(w2, k1.z, acc1[2]);
        acc0[3] = fmaf(w3, k0.w, acc0[3]); acc1[3] = fmaf(w3, k1.w, acc1[3]);
    };

    loadK(kA0, kA1, 0);
    #pragma unroll 1
    for (int i = 0; i < NPG - 1; i += 2) {
        loadK(kB0, kB1, i + 1);            // issue next before consuming current
        computeK(kA0, kA1, i);
        if (i + 2 < NPG) loadK(kA0, kA1, i + 2);
        computeK(kB0, kB1, i + 1);
    }
    computeK(kA0, kA1, NPG - 1);

    // ---- phase 4: spill per-wave partials ----
    {
        vfloat4 a; a.x = acc0[0]; a.y = acc0[1]; a.z = acc0[2]; a.w = acc0[3];
        *reinterpret_cast<vfloat4*>(&Pacc[(g * CB + cg) * TILE + vq * 4]) = a;
        vfloat4 c; c.x = acc1[0]; c.y = acc1[1]; c.z = acc1[2]; c.w = acc1[3];
        *reinterpret_cast<vfloat4*>(&Pacc[(g * CB + cg + 16) * TILE + vq * 4]) = c;
    }
    if (cg == 0) {
        vfloat4 lv; lv.x = l0; lv.y = l1; lv.z = l2; lv.w = l3;
        *reinterpret_cast<vfloat4*>(&l_prt[g * TILE + vq * 4]) = lv;
    }
    __syncthreads();

    // ---- phase 5: combine + LayerNorm + fused output (threads 0..15) ----
    if (t < TILE) {
        const float lt = l_prt[t] + l_prt[TILE + t] + l_prt[2 * TILE + t] + l_prt[3 * TILE + t];
        const float il = 1.f / lt;
        inv_l_s[t] = il;
        float f[CB], mu = 0.f;
        #pragma unroll
        for (int c = 0; c < CB; ++c) {
            f[c] = (Pacc[(0 * CB + c) * TILE + t] + Pacc[(1 * CB + c) * TILE + t] +
                    Pacc[(2 * CB + c) * TILE + t] + Pacc[(3 * CB + c) * TILE + t]) * il;
            mu += f[c];
        }
        mu *= (1.f / CB);
        float var = 0.f;
        #pragma unroll
        for (int c = 0; c < CB; ++c) { const float d = f[c] - mu; var = fmaf(d, d, var); }
        const float rs = rsqrtf(var * (1.f / CB) + 1e-5f);
        float* op = out + (size_t)b * CB * VV + v0 + t;
        #pragma unroll
        for (int c = 0; c < CB; ++c)
            op[(size_t)c * VV] = (f[c] - mu) * rs * gam_s[c] + bet_s[c];
    }
    __syncthreads();

    // ---- phase 6: normalized attn weights, float4 stores ----
    {
        const int v   = t & 15;
        const int seg = t >> 4;        // 0..15
        const float il = inv_l_s[v];
        float* arow = out + (size_t)BB * CB * VV + ((size_t)b * VV + v0 + v) * NN;
        #pragma unroll
        for (int k = 0; k < 3; ++k) {
            const int q4 = seg + (k << 4);
            if (q4 < NN / 4) {   // 45 float4 per row
                vfloat4 wv = *reinterpret_cast<const vfloat4*>(&W_t[v * NN + q4 * 4]);
                wv.x *= il; wv.y *= il; wv.z *= il; wv.w *= il;
                *reinterpret_cast<vfloat4*>(arow + q4 * 4) = wv;  // row base 720B aligned
            }
        }
    }
}

extern "C" void kernel_launch(void* const* d_in, const int* in_sizes, int n_in,
                              void* d_out, int out_size, void* d_ws, size_t ws_size,
                              hipStream_t stream) {
    (void)in_sizes; (void)n_in; (void)out_size; (void)d_ws; (void)ws_size;
    const float* ct   = (const float*)d_in[0];
    const float* beam = (const float*)d_in[1];
    const float* qw   = (const float*)d_in[2];
    const float* qb   = (const float*)d_in[3];
    const float* gam  = (const float*)d_in[4];
    const float* bet  = (const float*)d_in[5];
    float* out = (float*)d_out;
    dim3 grid(BB * NTILES);   // 1728 blocks -> 6.75 per CU, makespan loss ~3.7%
    vmat_attn_kernel<<<grid, THREADS, 0, stream>>>(ct, beam, qw, qb, gam, bet, out);
}

// Round 6
// 150.595 us; speedup vs baseline: 1.9262x; 1.9262x over previous
//
#include <hip/hip_runtime.h>
#include <math.h>

#define BB      2
#define C_CT    128
#define CB      32
#define NN      180
#define VV      13824      // 24*24*24
#define TILE    32         // voxels per block (= 128 B per channel: one full L2 line)
#define NTILES  (VV / TILE)   // 432 per batch -> 864 blocks total
#define GR      4          // n-groups (one per wave)
#define NPG     45         // NN / GR
#define THREADS 256

typedef float vfloat4 __attribute__((ext_vector_type(4)));

// LDS union layout (bytes), one block = 39936 + q_s handled inside:
//  phase 1-2 : [0,16896) qw_t fp32 [128][33] ; [16896,33280) ct_s fp32 [128][32]
//  phase 2-3 : [33280,37504) q_s fp32 [32][33]   (dead before Pacc is written)
//  phase 3+  : [0,23040) W_t fp32 [180][32] ; [23040,39424) Pacc [4][32][32];
//              [39424,39936) l_prt [4][32]
#define UNI_FLOATS 9984

__global__ __launch_bounds__(THREADS, 4)
void vmat_attn_kernel(const float* __restrict__ ct, const float* __restrict__ beam,
                      const float* __restrict__ qw, const float* __restrict__ qb,
                      const float* __restrict__ gam, const float* __restrict__ bet,
                      float* __restrict__ out)
{
    __shared__ __align__(16) float uni[UNI_FLOATS];
    __shared__ float inv_l_s[TILE];
    __shared__ float qb_s[CB], gam_s[CB], bet_s[CB];

    float* qw_t  = uni;                    // [128][33] (+1 pad: conflict-free)
    float* ct_s  = uni + 128 * 33;         // [128][32]
    float* q_s   = uni + 8320;             // [32][33]  (float idx 8320 = byte 33280)
    float* W_t   = uni;                    // [180][32] unnormalized weights, [n][vox]
    float* Pacc  = uni + 5760;             // [4][32][32]
    float* l_prt = uni + 5760 + 4096;      // [4][32]

    const int t   = threadIdx.x;
    const int bid = blockIdx.x;
    const int b   = bid / NTILES;
    const int v0  = (bid % NTILES) * TILE;

    // ---- phase 1: stage qw (transposed, padded) + ct tile + params ----
    for (int i = t; i < CB * C_CT; i += THREADS) {
        const int o = i >> 7, c = i & 127;
        qw_t[c * 33 + o] = qw[i];
    }
    {
        const float* ctbase = ct + (size_t)b * C_CT * VV + v0;
        for (int i = t; i < C_CT * 8; i += THREADS) {   // 1024 float4
            const int c = i >> 3, qd = i & 7;
            *reinterpret_cast<vfloat4*>(&ct_s[c * TILE + qd * 4]) =
                *reinterpret_cast<const vfloat4*>(ctbase + (size_t)c * VV + qd * 4);
        }
    }
    if (t < CB) { qb_s[t] = qb[t]; gam_s[t] = gam[t]; bet_s[t] = bet[t]; }
    __syncthreads();

    // ---- phase 2: q = qw @ ct tile (32x32x128 LDS GEMM; 4 voxels/thread) ----
    {
        const int o  = t & 31;
        const int va = t >> 5;               // voxels va, va+8, va+16, va+24
        float a0 = qb_s[o], a1 = qb_s[o], a2 = qb_s[o], a3 = qb_s[o];
        for (int k = 0; k < C_CT; ++k) {
            const float wk = qw_t[k * 33 + o];           // conflict-free
            const float* cr = &ct_s[k * TILE];
            a0 = fmaf(wk, cr[va],      a0);              // broadcast reads
            a1 = fmaf(wk, cr[va + 8],  a1);
            a2 = fmaf(wk, cr[va + 16], a2);
            a3 = fmaf(wk, cr[va + 24], a3);
        }
        q_s[(va)      * 33 + o] = a0;
        q_s[(va + 8)  * 33 + o] = a1;
        q_s[(va + 16) * 33 + o] = a2;
        q_s[(va + 24) * 33 + o] = a3;
    }
    __syncthreads();

    // ---- phase 3: fused logits + exp + weighted accum (waves split N) ----
    const int lane = t & 63;
    const int g    = t >> 6;        // wave = n-group
    const int vq   = lane & 7;      // voxel quad (voxels vq*4..vq*4+3)
    const int cg   = lane >> 3;     // 0..7 ; channels cg+8k, k=0..3

    float q[4][4];                  // [k][voxel j]
    #pragma unroll
    for (int k = 0; k < 4; ++k)
        #pragma unroll
        for (int j = 0; j < 4; ++j)
            q[k][j] = q_s[(vq * 4 + j) * 33 + cg + 8 * k];   // ~2-way banks
    __syncthreads();   // q_s dead; uni becomes W_t/Pacc/l_prt

    const float scale = 0.17677669529663687f;  // 32^-0.5
    float acc[4][4];
    #pragma unroll
    for (int k = 0; k < 4; ++k)
        acc[k][0] = acc[k][1] = acc[k][2] = acc[k][3] = 0.f;
    float l0 = 0.f, l1 = 0.f, l2 = 0.f, l3 = 0.f;
    const float* bpc = beam + ((size_t)(b * NN + g * NPG) * CB + cg) * VV + v0 + vq * 4;

    vfloat4 kvA[4], kvB[4];
    auto loadK = [&](vfloat4* kv, int i) {
        const float* p = bpc + (size_t)i * (CB * VV);
        #pragma unroll
        for (int k = 0; k < 4; ++k)   // channels cg, cg+8, cg+16, cg+24
            kv[k] = __builtin_nontemporal_load(
                reinterpret_cast<const vfloat4*>(p + (size_t)(8 * k) * VV));
    };
    auto computeK = [&](const vfloat4* kv, int i) {
        float p0 = q[0][0] * kv[0].x, p1 = q[0][1] * kv[0].y;
        float p2 = q[0][2] * kv[0].z, p3 = q[0][3] * kv[0].w;
        #pragma unroll
        for (int k = 1; k < 4; ++k) {
            p0 = fmaf(q[k][0], kv[k].x, p0);
            p1 = fmaf(q[k][1], kv[k].y, p1);
            p2 = fmaf(q[k][2], kv[k].z, p2);
            p3 = fmaf(q[k][3], kv[k].w, p3);
        }
        p0 += __shfl_xor(p0, 8);  p1 += __shfl_xor(p1, 8);
        p2 += __shfl_xor(p2, 8);  p3 += __shfl_xor(p3, 8);
        p0 += __shfl_xor(p0, 16); p1 += __shfl_xor(p1, 16);
        p2 += __shfl_xor(p2, 16); p3 += __shfl_xor(p3, 16);
        p0 += __shfl_xor(p0, 32); p1 += __shfl_xor(p1, 32);
        p2 += __shfl_xor(p2, 32); p3 += __shfl_xor(p3, 32);
        const float w0 = __expf(fminf(p0 * scale, 60.f));
        const float w1 = __expf(fminf(p1 * scale, 60.f));
        const float w2 = __expf(fminf(p2 * scale, 60.f));
        const float w3 = __expf(fminf(p3 * scale, 60.f));
        if (cg == 0) {   // 8 lanes write 128 consecutive bytes: conflict-free
            vfloat4 wv; wv.x = w0; wv.y = w1; wv.z = w2; wv.w = w3;
            *reinterpret_cast<vfloat4*>(&W_t[(g * NPG + i) * TILE + vq * 4]) = wv;
        }
        l0 += w0; l1 += w1; l2 += w2; l3 += w3;
        #pragma unroll
        for (int k = 0; k < 4; ++k) {
            acc[k][0] = fmaf(w0, kv[k].x, acc[k][0]);
            acc[k][1] = fmaf(w1, kv[k].y, acc[k][1]);
            acc[k][2] = fmaf(w2, kv[k].z, acc[k][2]);
            acc[k][3] = fmaf(w3, kv[k].w, acc[k][3]);
        }
    };

    loadK(kvA, 0);
    #pragma unroll 1
    for (int i = 0; i < NPG - 1; i += 2) {
        loadK(kvB, i + 1);            // issue next before consuming current
        computeK(kvA, i);
        if (i + 2 < NPG) loadK(kvA, i + 2);
        computeK(kvB, i + 1);
    }
    computeK(kvA, NPG - 1);

    // ---- phase 4: spill per-wave partials ----
    #pragma unroll
    for (int k = 0; k < 4; ++k) {
        vfloat4 a; a.x = acc[k][0]; a.y = acc[k][1]; a.z = acc[k][2]; a.w = acc[k][3];
        *reinterpret_cast<vfloat4*>(&Pacc[(g * CB + cg + 8 * k) * TILE + vq * 4]) = a;
    }
    if (cg == 0) {
        vfloat4 lv; lv.x = l0; lv.y = l1; lv.z = l2; lv.w = l3;
        *reinterpret_cast<vfloat4*>(&l_prt[g * TILE + vq * 4]) = lv;
    }
    __syncthreads();

    // ---- phase 5: combine + LayerNorm + fused output (threads 0..31) ----
    if (t < TILE) {
        const float lt = l_prt[t] + l_prt[TILE + t] + l_prt[2 * TILE + t] + l_prt[3 * TILE + t];
        const float il = 1.f / lt;
        inv_l_s[t] = il;
        float f[CB], mu = 0.f;
        #pragma unroll
        for (int c = 0; c < CB; ++c) {   // bank = t for every read: conflict-free
            f[c] = (Pacc[(0 * CB + c) * TILE + t] + Pacc[(1 * CB + c) * TILE + t] +
                    Pacc[(2 * CB + c) * TILE + t] + Pacc[(3 * CB + c) * TILE + t]) * il;
            mu += f[c];
        }
        mu *= (1.f / CB);
        float var = 0.f;
        #pragma unroll
        for (int c = 0; c < CB; ++c) { const float d = f[c] - mu; var = fmaf(d, d, var); }
        const float rs = rsqrtf(var * (1.f / CB) + 1e-5f);
        float* op = out + (size_t)b * CB * VV + v0 + t;
        #pragma unroll
        for (int c = 0; c < CB; ++c)
            op[(size_t)c * VV] = (f[c] - mu) * rs * gam_s[c] + bet_s[c];
    }
    __syncthreads();

    // ---- phase 6: normalized attn weights, float4 stores ----
    {
        const int v   = t & 31;
        const int seg = t >> 5;        // 0..7
        const float il = inv_l_s[v];
        float* arow = out + (size_t)BB * CB * VV + ((size_t)b * VV + v0 + v) * NN;
        #pragma unroll
        for (int k = 0; k < 6; ++k) {
            const int q4 = seg + (k << 3);
            if (q4 < NN / 4) {   // 45 float4 per row
                vfloat4 wv;
                wv.x = W_t[(q4 * 4 + 0) * TILE + v] * il;   // 2-way banks: free
                wv.y = W_t[(q4 * 4 + 1) * TILE + v] * il;
                wv.z = W_t[(q4 * 4 + 2) * TILE + v] * il;
                wv.w = W_t[(q4 * 4 + 3) * TILE + v] * il;
                *reinterpret_cast<vfloat4*>(arow + q4 * 4) = wv;  // row base 720B aligned
            }
        }
    }
}

extern "C" void kernel_launch(void* const* d_in, const int* in_sizes, int n_in,
                              void* d_out, int out_size, void* d_ws, size_t ws_size,
                              hipStream_t stream) {
    (void)in_sizes; (void)n_in; (void)out_size; (void)d_ws; (void)ws_size;
    const float* ct   = (const float*)d_in[0];
    const float* beam = (const float*)d_in[1];
    const float* qw   = (const float*)d_in[2];
    const float* qb   = (const float*)d_in[3];
    const float* gam  = (const float*)d_in[4];
    const float* bet  = (const float*)d_in[5];
    float* out = (float*)d_out;
    dim3 grid(BB * NTILES);   // 864 blocks; 4/CU resident -> all co-resident, no tail
    vmat_attn_kernel<<<grid, THREADS, 0, stream>>>(ct, beam, qw, qb, gam, bet, out);
}